// Round 1
// baseline (246.379 us; speedup 1.0000x reference)
//
#include <hip/hip_runtime.h>

// WaveConv1d on MI355X — round 12: einsum_v6.
//   out = x + idwt(E1(lo4)-lo4, E2(h4)-h4, 0, 0, 0)
// r11 analysis: einsum_v5 was LDS-instruction-rate bound (16x ds_read_b32 for w
// per thread/chunk = 93cy of the 161cy/wave/chunk LDS budget) + 4.5-block/CU
// grid imbalance + 41% occupancy. v6: (a) Wb stored j-contiguous so each ii is
// ONE ds_read_b128 (conflict-free 16B/lane); (b) i-reduction split in half ->
// grid 2304 (exactly 9 blocks/CU, 6 resident on 24KB LDS, ~75% occupancy),
// halves combined via atomicAdd into dlo/dh zero-initialized by xpose2.
// kt=8 tail overlaps kt=7 in k: tail blocks only write lanes with k>=512
// (plain-store overlap was benign, atomicAdd overlap would double-count).

#define NROWS 4096          // B*C
#define MODES 522

#define M1 4101
#define M2 2056
#define M3 1033
#define M4 522

typedef unsigned int  uint;
typedef unsigned short ushort;

__constant__ float c_dlo[12] = {
  -0.00107730108499558f,  0.004777257511010651f,  0.0005538422009938016f,
  -0.031582039318031156f, 0.02752286553001629f,   0.09750160558707936f,
  -0.12976686756709563f,  -0.22626469396516913f,  0.3152503517092432f,
   0.7511339080215775f,   0.4946238903983854f,    0.11154074335008017f };
__constant__ float c_dhi[12] = {
  -0.11154074335008017f,  0.4946238903983854f,   -0.7511339080215775f,
   0.3152503517092432f,   0.22626469396516913f,  -0.12976686756709563f,
  -0.09750160558707936f,  0.02752286553001629f,   0.031582039318031156f,
   0.0005538422009938016f,-0.004777257511010651f, -0.00107730108499558f };
// Analysis (time-reversed) filters
__constant__ float c_alo[12] = {
   0.11154074335008017f,  0.4946238903983854f,    0.7511339080215775f,
   0.3152503517092432f,  -0.22626469396516913f,  -0.12976686756709563f,
   0.09750160558707936f,  0.02752286553001629f,  -0.031582039318031156f,
   0.0005538422009938016f, 0.004777257511010651f, -0.00107730108499558f };
__constant__ float c_ahi[12] = {
  -0.00107730108499558f, -0.004777257511010651f,  0.0005538422009938016f,
   0.031582039318031156f, 0.02752286553001629f,  -0.09750160558707936f,
  -0.12976686756709563f,  0.22626469396516913f,   0.3152503517092432f,
  -0.7511339080215775f,   0.4946238903983854f,   -0.11154074335008017f };

__device__ __forceinline__ ushort f2bf(float f) {
    uint b = __float_as_uint(f);
    uint r = (b + 0x7fffu + ((b >> 16) & 1u)) >> 16;
    return (ushort)r;
}

// One lo-only analysis level LDS->LDS, interior fast path (no reflect).
__device__ __forceinline__
void dwt_lo_lds(const float* __restrict__ src, int n, int m,
                float* __restrict__ dst, int tid)
{
    int jhi = (n - 2) >> 1;
    for (int j = tid; j < m; j += 256) {
        float a = 0.f;
        if (j >= 5 && j <= jhi) {
            const float* s = src + 2 * j - 10;
#pragma unroll
            for (int t = 0; t < 12; ++t) a += s[t] * c_alo[t];
        } else {
            int base = 2 * j - 10;
#pragma unroll
            for (int t = 0; t < 12; ++t) {
                int u = base + t;
                u = (u < 0) ? (-1 - u) : u;
                u = (u >= n) ? (2 * n - 1 - u) : u;
                a += src[u] * c_alo[t];
            }
        }
        dst[j] = a;
    }
}

// Fused forward DWT, lo-chain only: x -> (lo4, h4). One block per row.
__global__ __launch_bounds__(256)
void dwt_fused2(const float* __restrict__ x,
                float* __restrict__ lo4g, float* __restrict__ h4g)
{
    __shared__ float X[8192];
    __shared__ float LA[4104];
    int row = blockIdx.x, tid = threadIdx.x;

    const float4* xr = (const float4*)(x + (size_t)row * 8192);
    float4* Xv = (float4*)X;
#pragma unroll
    for (int i = 0; i < 8; ++i) Xv[tid + 256 * i] = xr[tid + 256 * i];
    __syncthreads();

    dwt_lo_lds(X,  8192, M1, LA, tid);
    __syncthreads();
    dwt_lo_lds(LA, M1,   M2, X,  tid);
    __syncthreads();
    dwt_lo_lds(X,  M2,   M3, LA, tid);
    __syncthreads();

    float* lo4r = lo4g + (size_t)row * M4;
    float* h4r  = h4g  + (size_t)row * M4;
    int jhi = (M3 - 2) >> 1;
    for (int j = tid; j < M4; j += 256) {
        float alo = 0.f, ahi = 0.f;
        if (j >= 5 && j <= jhi) {
            const float* s = LA + 2 * j - 10;
#pragma unroll
            for (int t = 0; t < 12; ++t) {
                float v = s[t];
                alo += v * c_alo[t]; ahi += v * c_ahi[t];
            }
        } else {
            int base = 2 * j - 10;
#pragma unroll
            for (int t = 0; t < 12; ++t) {
                int u = base + t;
                u = (u < 0) ? (-1 - u) : u;
                u = (u >= M3) ? (2 * M3 - 1 - u) : u;
                float v = LA[u];
                alo += v * c_alo[t]; ahi += v * c_ahi[t];
            }
        }
        lo4r[j] = alo; h4r[j] = ahi;
    }
}

// xpose2: [b][c][k] fp32 -> bf16 xT [c][g=4][k=522][b4] (g = b>>2, b4 = b&3).
// One block per (c, tensor). ALSO zero-fills dlo/dh (2*SZ contiguous floats)
// for einsum_v6's atomicAdd accumulation (stream order guarantees completion
// before einsum launches).
__global__ __launch_bounds__(256)
void xpose2(const float* __restrict__ lo4, const float* __restrict__ h4,
            ushort* __restrict__ xlT, ushort* __restrict__ xhT,
            float* __restrict__ dzero)
{
    __shared__ float L[16][528];
    int c = blockIdx.x;
    const float* src = blockIdx.y ? h4 : lo4;
    ushort*      dst = blockIdx.y ? xhT : xlT;
    int t = threadIdx.x;

    // zero dlo+dh: 2*SZ floats = 1,069,056 float4s over 512 blocks x 256 thr
    {
        const size_t nz = ((size_t)2 * NROWS * M4) / 4;
        size_t gid = ((size_t)blockIdx.y * gridDim.x + blockIdx.x) * 256 + t;
        float4 z4 = make_float4(0.f, 0.f, 0.f, 0.f);
        float4* zp = (float4*)dzero;
        for (size_t i = gid; i < nz; i += (size_t)512 * 256) zp[i] = z4;
    }

#pragma unroll
    for (int b = 0; b < 16; ++b)
        for (int k = t; k < MODES; k += 256)
            L[b][k] = src[((size_t)b * 256 + c) * MODES + k];
    __syncthreads();

#pragma unroll
    for (int g = 0; g < 4; ++g) {
        for (int k = t; k < MODES; k += 256) {
            ushort4 v;
            v.x = f2bf(L[4*g+0][k]);
            v.y = f2bf(L[4*g+1][k]);
            v.z = f2bf(L[4*g+2][k]);
            v.w = f2bf(L[4*g+3][k]);
            *(ushort4*)&dst[(((size_t)c * 4 + g) * MODES + k) * 4] = v;
        }
    }
}

// Delta-IDWT: A = dlo-lo4, Hs = dh-h4; lvl4 full -> lvl3,2,1 lo-only -> +x.
__global__ __launch_bounds__(256)
void idwt_delta2(const float* __restrict__ dlo, const float* __restrict__ dh,
                 const float* __restrict__ lo4, const float* __restrict__ h4,
                 const float* __restrict__ x,   float* __restrict__ out)
{
    __shared__ float A[2056];
    __shared__ float B[4104];
    __shared__ float Hs[528];
    int row = blockIdx.x, tid = threadIdx.x;

    for (int i = tid; i < M4; i += 256) {
        size_t idx = (size_t)row * M4 + i;
        A[i]  = dlo[idx] - lo4[idx];
        Hs[i] = dh[idx]  - h4[idx];
    }
    __syncthreads();

    for (int jj = tid; jj < M4 - 5; jj += 256) {
        float e = 0.f, od = 0.f;
#pragma unroll
        for (int s = 0; s < 6; ++s) {
            float xv = A[jj + s], hv = Hs[jj + s];
            e  += xv * c_dlo[2*s+1] + hv * c_dhi[2*s+1];
            od += xv * c_dlo[2*s]   + hv * c_dhi[2*s];
        }
        B[2*jj] = e; B[2*jj+1] = od;
    }
    __syncthreads();

    for (int jj = tid; jj < M3 - 5; jj += 256) {
        float e = 0.f, od = 0.f;
#pragma unroll
        for (int s = 0; s < 6; ++s) {
            float xv = B[jj + s];
            e  += xv * c_dlo[2*s+1];
            od += xv * c_dlo[2*s];
        }
        A[2*jj] = e; A[2*jj+1] = od;
    }
    __syncthreads();

    for (int jj = tid; jj < M2 - 5; jj += 256) {
        float e = 0.f, od = 0.f;
#pragma unroll
        for (int s = 0; s < 6; ++s) {
            float xv = A[jj + s];
            e  += xv * c_dlo[2*s+1];
            od += xv * c_dlo[2*s];
        }
        B[2*jj] = e; B[2*jj+1] = od;
    }
    __syncthreads();

    const float2* x2 = (const float2*)(x + (size_t)row * 8192);
    float2* o2 = (float2*)(out + (size_t)row * 8192);
    for (int jj = tid; jj < M1 - 5; jj += 256) {
        float e = 0.f, od = 0.f;
#pragma unroll
        for (int s = 0; s < 6; ++s) {
            float xv = B[jj + s];
            e  += xv * c_dlo[2*s+1];
            od += xv * c_dlo[2*s];
        }
        float2 xv2 = x2[jj];
        o2[jj] = make_float2(xv2.x + e, xv2.y + od);
    }
}

// Dual einsum v6: split-i halves + j-contiguous Wb.
// dlo[b,o,k] += sum_{i in half} x[b,i,k]*w[i,o,k]   (atomicAdd; dlo/dh zeroed
// by xpose2; subtract of lo4/h4 happens in idwt_delta2).
// Grid 2304: wg<1152 -> (xlT,w1,dlo), else (xhT,w2,dh). Per tensor:
//   wg<1024: kt=wg&7 (XCD-pinned), r=wg>>3, oq=r&63, ih=r>>6
//   else:    kt=8 -> kbase=MODES-64, u=wg-1024, oq=u&63, ih=u>>6
// Each block: 32 chunks x 4 i over i in [ih*128, ih*128+128).
// Per chunk/thread staging: 2 dwordx4 (x bf16, unchanged) + 4 dword (w, one
// per j at stride MODES). Wb layout [(il*64+kk)*4 + j] -> compute reads ONE
// ds_read_b128 per ii (16B/lane contiguous, conflict-free) instead of 4x b32.
// kt=8 k-overlap with kt=7: only lanes with kbase+lane>=512 write.
__global__ __launch_bounds__(256)
void einsum_v6(const ushort* __restrict__ xlT, const ushort* __restrict__ xhT,
               const float* __restrict__ w1,   const float* __restrict__ w2,
               float* __restrict__ dlo, float* __restrict__ dh)
{
    __shared__ ushort Xb[2][4096];   // [buf][ ((il*4+g)*64 + kk)*4 + b ]  16 KB
    __shared__ float  Wb[2][1024];   // [buf][ (il*64 + kk)*4 + j ]         8 KB

    int wg = blockIdx.x;
    int e = (wg >= 1152); if (e) wg -= 1152;
    const ushort* xT = e ? xhT : xlT;
    const float*  w  = e ? w2  : w1;
    float* outp      = e ? dh  : dlo;

    int kt, oq, ih;
    if (wg < 1024) { kt = wg & 7; int r2 = wg >> 3; oq = r2 & 63; ih = r2 >> 6; }
    else           { kt = 8; int u = wg - 1024;     oq = u & 63;  ih = u >> 6; }
    int kbase = (kt < 8) ? kt * 64 : (MODES - 64);
    int lane = threadIdx.x & 63;
    int wv   = threadIdx.x >> 6;
    int o    = oq * 4;
    int t    = threadIdx.x;
    int i0   = ih * 128;

    // x staging decode: run = t>>4 -> (xil = run>>2, g = run&3); piece = t&15
    int run = t >> 4, piece = t & 15;
    int xil = run >> 2, g = run & 3;
    const ushort* xrunb = xT + (((size_t)(i0 + xil) * 4 + g) * MODES + kbase) * 4
                             + piece * 16;
    const size_t xistr = (size_t)4 * MODES * 4;           // ushorts per i

    // w staging decode: wr = t>>6 (= il), kk = t&63; 4 dword loads, one per j.
    int wr = t >> 6, kk = t & 63;
    const float* wrunb = w + ((size_t)(i0 + wr) * 256 + o) * MODES + kbase + kk;
    const size_t wistr = (size_t)256 * MODES;             // floats per i

    float acc[4][4];
#pragma unroll
    for (int q = 0; q < 4; ++q)
#pragma unroll
        for (int j = 0; j < 4; ++j) acc[q][j] = 0.f;

    // ---- prologue: stage chunk 0 (i = i0..i0+3) ----
    {
        uint4 v0 = *(const uint4*)(xrunb);
        uint4 v1 = *(const uint4*)(xrunb + 8);
        float f0 = wrunb[0];
        float f1 = wrunb[MODES];
        float f2 = wrunb[2 * MODES];
        float f3 = wrunb[3 * MODES];
        uint4* xd = (uint4*)&Xb[0][t * 16];
        xd[0] = v0; xd[1] = v1;
        *(float4*)&Wb[0][t * 4] = make_float4(f0, f1, f2, f3);
    }
    __syncthreads();

    for (int ch = 0; ch < 32; ++ch) {
        int cur = ch & 1, nb = cur ^ 1;
        uint4 v0, v1; float f0, f1, f2, f3;
        if (ch < 31) {
            const ushort* xs = xrunb + (size_t)(ch + 1) * 4 * xistr;
            v0 = *(const uint4*)(xs);
            v1 = *(const uint4*)(xs + 8);
            const float* wsv = wrunb + (size_t)(ch + 1) * 4 * wistr;
            f0 = wsv[0]; f1 = wsv[MODES]; f2 = wsv[2 * MODES]; f3 = wsv[3 * MODES];
        }

        // compute chunk ch from buf cur
#pragma unroll
        for (int ii = 0; ii < 4; ++ii) {
            uint2 xp = *(const uint2*)&Xb[cur][(((ii * 4) + wv) * 64 + lane) * 4];
            float4 w4 = *(const float4*)&Wb[cur][(ii * 64 + lane) * 4];
            float x0 = __uint_as_float(xp.x << 16);
            float x1 = __uint_as_float(xp.x & 0xffff0000u);
            float x2 = __uint_as_float(xp.y << 16);
            float x3 = __uint_as_float(xp.y & 0xffff0000u);
            acc[0][0] += x0 * w4.x; acc[0][1] += x0 * w4.y;
            acc[0][2] += x0 * w4.z; acc[0][3] += x0 * w4.w;
            acc[1][0] += x1 * w4.x; acc[1][1] += x1 * w4.y;
            acc[1][2] += x1 * w4.z; acc[1][3] += x1 * w4.w;
            acc[2][0] += x2 * w4.x; acc[2][1] += x2 * w4.y;
            acc[2][2] += x2 * w4.z; acc[2][3] += x2 * w4.w;
            acc[3][0] += x3 * w4.x; acc[3][1] += x3 * w4.y;
            acc[3][2] += x3 * w4.z; acc[3][3] += x3 * w4.w;
        }

        if (ch < 31) {
            uint4* xd = (uint4*)&Xb[nb][t * 16];
            xd[0] = v0; xd[1] = v1;
            *(float4*)&Wb[nb][t * 4] = make_float4(f0, f1, f2, f3);
        }
        __syncthreads();
    }

    // atomic accumulate (each element hit exactly twice: ih=0 and ih=1).
    // kt=8 overlaps kt=7 for k in [458,512): those lanes must not write.
    bool wrk = (kt < 8) || (kbase + lane >= 512);
    if (wrk) {
#pragma unroll
        for (int q = 0; q < 4; ++q) {
            int b = 4 * wv + q;
#pragma unroll
            for (int j = 0; j < 4; ++j)
                atomicAdd(&outp[((size_t)b * 256 + o + j) * MODES + kbase + lane],
                          acc[q][j]);
        }
    }
}

extern "C" void kernel_launch(void* const* d_in, const int* in_sizes, int n_in,
                              void* d_out, int out_size, void* d_ws, size_t ws_size,
                              hipStream_t stream)
{
    const float* x  = (const float*)d_in[0];
    const float* w1 = (const float*)d_in[1];
    const float* w2 = (const float*)d_in[2];
    float* out = (float*)d_out;
    float* ws  = (float*)d_ws;

    const size_t SZ = (size_t)NROWS * M4;   // 2,138,112
    float* lo4 = ws;
    float* h4  = lo4 + SZ;
    float* dlo = h4  + SZ;
    float* dh  = dlo + SZ;                   // dlo,dh contiguous (zeroed together)
    ushort* xlT = (ushort*)(dh + SZ);        // SZ ushorts
    ushort* xhT = xlT + SZ;                  // SZ ushorts

    dim3 blk(256);

    dwt_fused2<<<NROWS, blk, 0, stream>>>(x, lo4, h4);
    xpose2<<<dim3(256, 2), blk, 0, stream>>>(lo4, h4, xlT, xhT, dlo);
    einsum_v6<<<2304, blk, 0, stream>>>(xlT, xhT, w1, w2, dlo, dh);
    idwt_delta2<<<NROWS, blk, 0, stream>>>(dlo, dh, lo4, h4, x, out);
}